// Round 1
// baseline (2835.012 us; speedup 1.0000x reference)
//
#include <hip/hip_runtime.h>
#include <cstddef>

#define NS 512
#define NL 5
#define NT 20
#define NE 768
#define NH 64
#define NG 256   // 4*H
#define BK 16

__device__ __forceinline__ float sigf(float x) { return 1.0f / (1.0f + expf(-x)); }

// ---------------------------------------------------------------------------
// Kernel 1: u[s][t][l][g] = sum_e x[s][l][t][e] * Uall[s][e][g] + bUall[s][g]
// one block per stock, 640 threads; thread tile = 10 rows x 4 cols
// ---------------------------------------------------------------------------
__global__ __launch_bounds__(640) void k_gemm_u(
    const float* __restrict__ x, const float* __restrict__ U,
    const float* __restrict__ bU, float* __restrict__ u)
{
    __shared__ float xs[100 * BK];   // x tile [row][k]
    __shared__ float Us[BK * NG];    // U tile [k][c]
    const int s = blockIdx.x;
    const int tid = threadIdx.x;
    const float* xg = x + (size_t)s * (NL * NT * NE);
    const float* Ug = U + (size_t)s * (NE * NG);
    const int rg = tid >> 6;    // wave id 0..9 -> row group (wave-uniform)
    const int cg = tid & 63;
    const int r0 = rg * 10;
    const int c0 = cg * 4;
    float acc[10][4];
    #pragma unroll
    for (int i = 0; i < 10; ++i)
        acc[i][0] = acc[i][1] = acc[i][2] = acc[i][3] = 0.0f;

    for (int e0 = 0; e0 < NE; e0 += BK) {
        if (tid < 400) {
            int row = tid >> 2;
            int kq = (tid & 3) * 4;
            *(float4*)&xs[row * BK + kq] =
                *(const float4*)(xg + (size_t)row * NE + e0 + kq);
        }
        {
            int i = tid;
            if (i < 1024) {
                int k = i >> 6, c4 = (i & 63) * 4;
                *(float4*)&Us[k * NG + c4] =
                    *(const float4*)(Ug + (size_t)(e0 + k) * NG + c4);
            }
            i = tid + 640;
            if (i < 1024) {
                int k = i >> 6, c4 = (i & 63) * 4;
                *(float4*)&Us[k * NG + c4] =
                    *(const float4*)(Ug + (size_t)(e0 + k) * NG + c4);
            }
        }
        __syncthreads();
        #pragma unroll
        for (int k4 = 0; k4 < BK; k4 += 4) {
            float4 uq0 = *(const float4*)&Us[(k4 + 0) * NG + c0];
            float4 uq1 = *(const float4*)&Us[(k4 + 1) * NG + c0];
            float4 uq2 = *(const float4*)&Us[(k4 + 2) * NG + c0];
            float4 uq3 = *(const float4*)&Us[(k4 + 3) * NG + c0];
            #pragma unroll
            for (int rr = 0; rr < 10; ++rr) {
                float4 xv = *(const float4*)&xs[(r0 + rr) * BK + k4];
                acc[rr][0] += xv.x * uq0.x + xv.y * uq1.x + xv.z * uq2.x + xv.w * uq3.x;
                acc[rr][1] += xv.x * uq0.y + xv.y * uq1.y + xv.z * uq2.y + xv.w * uq3.y;
                acc[rr][2] += xv.x * uq0.z + xv.y * uq1.z + xv.z * uq2.z + xv.w * uq3.z;
                acc[rr][3] += xv.x * uq0.w + xv.y * uq1.w + xv.z * uq2.w + xv.w * uq3.w;
            }
        }
        __syncthreads();
    }
    float4 bv = *(const float4*)(bU + (size_t)s * NG + c0);
    #pragma unroll
    for (int rr = 0; rr < 10; ++rr) {
        int r = r0 + rr;
        int l = r / 20, t = r % 20;   // x row index r = l*T + t
        float4 o;
        o.x = acc[rr][0] + bv.x;
        o.y = acc[rr][1] + bv.y;
        o.z = acc[rr][2] + bv.z;
        o.w = acc[rr][3] + bv.w;
        *(float4*)(u + (((size_t)s * NT + t) * NL + l) * NG + c0) = o;
    }
}

// ---------------------------------------------------------------------------
// Kernel 2: per-stock TimeLSTM + text attention + day LSTM + day attention + head
// one block per stock, 256 threads. Phase-aliased LDS layout (64.3 KB):
//   OF_FULL: full[L][T][H] -> (day phase) gbufL@0, hd@1536
//   OF_REGA: Wd -> W1 ;  OF_REGB: gbufR(recurrence) -> W2
//   OF_CS: c -> score(100) -> s2(5) ; OF_CA: c_adj -> text_vec
//   OF_TQ: ts(100) -> q(320) ; OF_CB0: bWd -> b1
// ---------------------------------------------------------------------------
#define OF_FULL  0
#define OF_REGA  6400
#define OF_REGB  10496
#define OF_CS    14592
#define OF_HS    14912
#define OF_CA    15232
#define OF_TQ    15552
#define OF_CB0   15872
#define OF_CB1   15936
#define OF_CB2   16000
#define OF_BV    16064
#define SM_TOT   16065

__global__ __launch_bounds__(256) void k_stock(
    const float* __restrict__ u, const float* __restrict__ ti,
    const float* __restrict__ Wall, const float* __restrict__ bWall,
    const float* __restrict__ Wd, const float* __restrict__ bWd,
    const float* __restrict__ W1, const float* __restrict__ b1,
    const float* __restrict__ W2, const float* __restrict__ b2,
    const float* __restrict__ V, const float* __restrict__ bV,
    const float* __restrict__ Wih, const float* __restrict__ bih,
    const float* __restrict__ bhh, const float* __restrict__ lin_w,
    const float* __restrict__ lin_b, float* __restrict__ out)
{
    __shared__ float sm[SM_TOT];
    const int s = blockIdx.x;
    const int tid = threadIdx.x;
    const float* ug = u + (size_t)s * NT * NL * NG;

    // ---- init: Wall column in registers, Wd/bWd/ts to LDS, zero state ----
    float wreg[NH];
    #pragma unroll
    for (int k = 0; k < NH; ++k)
        wreg[k] = Wall[((size_t)s * NH + k) * NG + tid];
    const float bwall_r = bWall[(size_t)s * NG + tid];

    for (int i = tid; i < NH * NH; i += 256)
        sm[OF_REGA + i] = Wd[(size_t)s * NH * NH + i];
    if (tid < NH) sm[OF_CB0 + tid] = bWd[(size_t)s * NH + tid];
    if (tid < NL * NT) sm[OF_TQ + tid] = ti[(size_t)s * NL * NT + tid];
    for (int idx = tid; idx < NL * NH; idx += 256) {
        sm[OF_CS + idx] = 0.0f;
        sm[OF_HS + idx] = 0.0f;
    }
    float uc[NL];
    #pragma unroll
    for (int l = 0; l < NL; ++l)
        uc[l] = ug[(size_t)l * NG + tid];
    __syncthreads();

    // ---- TimeLSTM over T steps (gate order f,i,o,c_tmp; ALL sigmoid) ----
    for (int t = 0; t < NT; ++t) {
        float un[NL];
        if (t + 1 < NT) {
            #pragma unroll
            for (int l = 0; l < NL; ++l)
                un[l] = ug[(size_t)((t + 1) * NL + l) * NG + tid];
        } else {
            #pragma unroll
            for (int l = 0; l < NL; ++l) un[l] = 0.0f;
        }
        // gate pre-activation for column tid (u already includes bUall)
        float gv[NL];
        #pragma unroll
        for (int l = 0; l < NL; ++l) gv[l] = bwall_r + uc[l];
        #pragma unroll
        for (int k4 = 0; k4 < NH; k4 += 4) {
            #pragma unroll
            for (int l = 0; l < NL; ++l) {
                float4 hv = *(const float4*)&sm[OF_HS + l * NH + k4];
                gv[l] += hv.x * wreg[k4] + hv.y * wreg[k4 + 1] +
                         hv.z * wreg[k4 + 2] + hv.w * wreg[k4 + 3];
            }
        }
        #pragma unroll
        for (int l = 0; l < NL; ++l)
            sm[OF_REGB + l * NG + tid] = sigf(gv[l]);
        // c_s1 = tanh(c@Wd + bWd); c_adj = c - c_s1 + c_s1*ts
        for (int idx = tid; idx < NL * NH; idx += 256) {
            int l = idx >> 6, hh = idx & 63;
            float ssum = sm[OF_CB0 + hh];
            #pragma unroll
            for (int k4 = 0; k4 < NH; k4 += 4) {
                float4 cv = *(const float4*)&sm[OF_CS + l * NH + k4];
                ssum += cv.x * sm[OF_REGA + (k4 + 0) * NH + hh]
                      + cv.y * sm[OF_REGA + (k4 + 1) * NH + hh]
                      + cv.z * sm[OF_REGA + (k4 + 2) * NH + hh]
                      + cv.w * sm[OF_REGA + (k4 + 3) * NH + hh];
            }
            float cs1 = tanhf(ssum);
            float tsv = sm[OF_TQ + l * NT + t];
            sm[OF_CA + idx] = sm[OF_CS + idx] - cs1 + cs1 * tsv;
        }
        __syncthreads();
        for (int idx = tid; idx < NL * NH; idx += 256) {
            int l = idx >> 6, hh = idx & 63;
            float f  = sm[OF_REGB + l * NG + hh];
            float ii = sm[OF_REGB + l * NG + 64 + hh];
            float oo = sm[OF_REGB + l * NG + 128 + hh];
            float ct = sm[OF_REGB + l * NG + 192 + hh];
            float cn = f * sm[OF_CA + idx] + ii * ct;
            sm[OF_CS + idx] = cn;
            sm[OF_HS + idx] = oo * tanhf(cn);
            sm[OF_FULL + (l * NT + t) * NH + hh] = oo;
        }
        __syncthreads();
        #pragma unroll
        for (int l = 0; l < NL; ++l) uc[l] = un[l];
    }

    // ---- load attention weights (Wd/gbufR/bWd now dead) ----
    for (int i = tid; i < NH * NH; i += 256) {
        sm[OF_REGA + i] = W1[(size_t)s * NH * NH + i];
        sm[OF_REGB + i] = W2[(size_t)s * NH * NH + i];
    }
    if (tid < NH) {
        sm[OF_CB0 + tid] = b1[(size_t)s * NH + tid];
        sm[OF_CB1 + tid] = b2[(size_t)s * NH + tid];
        sm[OF_CB2 + tid] = V[(size_t)s * NH + tid];
    }
    if (tid == 0) sm[OF_BV] = bV[s];
    __syncthreads();

    // q = h_fin @ W1 + b1
    for (int idx = tid; idx < NL * NH; idx += 256) {
        int l = idx >> 6, hh = idx & 63;
        float qv = sm[OF_CB0 + hh];
        #pragma unroll
        for (int k4 = 0; k4 < NH; k4 += 4) {
            float4 hv = *(const float4*)&sm[OF_HS + l * NH + k4];
            qv += hv.x * sm[OF_REGA + (k4 + 0) * NH + hh]
                + hv.y * sm[OF_REGA + (k4 + 1) * NH + hh]
                + hv.z * sm[OF_REGA + (k4 + 2) * NH + hh]
                + hv.w * sm[OF_REGA + (k4 + 3) * NH + hh];
        }
        sm[OF_TQ + idx] = qv;
    }
    __syncthreads();

    // scores: one wave per (l,t); score = tanh(q + full@W2 + b2) . V + bV
    const int wid = tid >> 6, lane = tid & 63;
    for (int lt = wid; lt < NL * NT; lt += 4) {
        int l = lt / NT;
        float v = sm[OF_TQ + l * NH + lane] + sm[OF_CB1 + lane];
        #pragma unroll
        for (int k4 = 0; k4 < NH; k4 += 4) {
            float4 fv = *(const float4*)&sm[OF_FULL + lt * NH + k4];
            v += fv.x * sm[OF_REGB + (k4 + 0) * NH + lane]
               + fv.y * sm[OF_REGB + (k4 + 1) * NH + lane]
               + fv.z * sm[OF_REGB + (k4 + 2) * NH + lane]
               + fv.w * sm[OF_REGB + (k4 + 3) * NH + lane];
        }
        v = tanhf(v) * sm[OF_CB2 + lane];
        #pragma unroll
        for (int m = 32; m > 0; m >>= 1) v += __shfl_xor(v, m, 64);
        if (lane == 0) sm[OF_CS + lt] = v + sm[OF_BV];
    }
    __syncthreads();

    // softmax over t per l (stable)
    if (tid < NL) {
        float mx = -1e30f;
        for (int t = 0; t < NT; ++t) mx = fmaxf(mx, sm[OF_CS + tid * NT + t]);
        float sum = 0.0f;
        for (int t = 0; t < NT; ++t) {
            float e = expf(sm[OF_CS + tid * NT + t] - mx);
            sm[OF_CS + tid * NT + t] = e;
            sum += e;
        }
        float inv = 1.0f / sum;
        for (int t = 0; t < NT; ++t) sm[OF_CS + tid * NT + t] *= inv;
    }
    __syncthreads();

    // text_vec = sum_t aw * full
    for (int idx = tid; idx < NL * NH; idx += 256) {
        int l = idx >> 6, hh = idx & 63;
        float sv = 0.0f;
        #pragma unroll
        for (int t = 0; t < NT; ++t)
            sv += sm[OF_CS + l * NT + t] * sm[OF_FULL + (l * NT + t) * NH + hh];
        sm[OF_CA + idx] = sv;   // tv
    }
    __syncthreads();

    // day LSTM: g = tv@Wih + bih + bhh (h0=0); gate order i,f,g,o
    {
        float bsum = bih[(size_t)s * NG + tid] + bhh[(size_t)s * NG + tid];
        float dsum[NL];
        #pragma unroll
        for (int l = 0; l < NL; ++l) dsum[l] = bsum;
        for (int k = 0; k < NH; ++k) {
            float wk = Wih[((size_t)s * NH + k) * NG + tid];
            #pragma unroll
            for (int l = 0; l < NL; ++l)
                dsum[l] += sm[OF_CA + l * NH + k] * wk;
        }
        #pragma unroll
        for (int l = 0; l < NL; ++l)
            sm[OF_FULL + l * NG + tid] = dsum[l];   // gbufL (full is dead)
    }
    __syncthreads();
    for (int idx = tid; idx < NL * NH; idx += 256) {
        int l = idx >> 6, hh = idx & 63;
        float gi = sm[OF_FULL + l * NG + hh];
        float gg = sm[OF_FULL + l * NG + 128 + hh];
        float go = sm[OF_FULL + l * NG + 192 + hh];
        float cd = sigf(gi) * tanhf(gg);
        sm[OF_FULL + 1536 + idx] = sigf(go) * tanhf(cd);   // hd
    }
    __syncthreads();

    // day attention: s2 = tanh(hd@W1 + b1 + hd@W2 + b2) . V + bV, softmax over L
    for (int l = wid; l < NL; l += 4) {
        float v = sm[OF_CB0 + lane] + sm[OF_CB1 + lane];
        #pragma unroll
        for (int k4 = 0; k4 < NH; k4 += 4) {
            float4 hv = *(const float4*)&sm[OF_FULL + 1536 + l * NH + k4];
            v += hv.x * (sm[OF_REGA + (k4 + 0) * NH + lane] + sm[OF_REGB + (k4 + 0) * NH + lane])
               + hv.y * (sm[OF_REGA + (k4 + 1) * NH + lane] + sm[OF_REGB + (k4 + 1) * NH + lane])
               + hv.z * (sm[OF_REGA + (k4 + 2) * NH + lane] + sm[OF_REGB + (k4 + 2) * NH + lane])
               + hv.w * (sm[OF_REGA + (k4 + 3) * NH + lane] + sm[OF_REGB + (k4 + 3) * NH + lane]);
        }
        v = tanhf(v) * sm[OF_CB2 + lane];
        #pragma unroll
        for (int m = 32; m > 0; m >>= 1) v += __shfl_xor(v, m, 64);
        if (lane == 0) sm[OF_CS + l] = v + sm[OF_BV];
    }
    __syncthreads();
    if (tid == 0) {
        float mx = -1e30f;
        for (int l = 0; l < NL; ++l) mx = fmaxf(mx, sm[OF_CS + l]);
        float sum = 0.0f;
        for (int l = 0; l < NL; ++l) {
            float e = expf(sm[OF_CS + l] - mx);
            sm[OF_CS + l] = e;
            sum += e;
        }
        float inv = 1.0f / sum;
        for (int l = 0; l < NL; ++l) sm[OF_CS + l] *= inv;
    }
    __syncthreads();

    // ft = sum_l aw2*hd ; out = leaky_relu(ft . lin_w + lin_b)
    if (tid < NH) {
        float fv = 0.0f;
        #pragma unroll
        for (int l = 0; l < NL; ++l)
            fv += sm[OF_CS + l] * sm[OF_FULL + 1536 + l * NH + tid];
        fv *= lin_w[tid];
        #pragma unroll
        for (int m = 32; m > 0; m >>= 1) fv += __shfl_xor(fv, m, 64);
        if (tid == 0) {
            float val = fv + lin_b[0];
            out[s] = val > 0.0f ? val : 0.01f * val;
        }
    }
}

extern "C" void kernel_launch(void* const* d_in, const int* in_sizes, int n_in,
                              void* d_out, int out_size, void* d_ws, size_t ws_size,
                              hipStream_t stream) {
    (void)in_sizes; (void)n_in; (void)out_size; (void)ws_size;
    const float* x     = (const float*)d_in[0];
    const float* ti    = (const float*)d_in[1];
    const float* Wall  = (const float*)d_in[2];
    const float* bWall = (const float*)d_in[3];
    const float* Uall  = (const float*)d_in[4];
    const float* bUall = (const float*)d_in[5];
    const float* Wd    = (const float*)d_in[6];
    const float* bWd   = (const float*)d_in[7];
    const float* W1    = (const float*)d_in[8];
    const float* b1    = (const float*)d_in[9];
    const float* W2    = (const float*)d_in[10];
    const float* b2    = (const float*)d_in[11];
    const float* V     = (const float*)d_in[12];
    const float* bV    = (const float*)d_in[13];
    const float* Wih   = (const float*)d_in[14];
    const float* bih   = (const float*)d_in[16];
    const float* bhh   = (const float*)d_in[17];
    const float* lin_w = (const float*)d_in[18];
    const float* lin_b = (const float*)d_in[19];
    float* out = (float*)d_out;
    float* u = (float*)d_ws;   // [S][T][L][NG] = 52.4 MB

    k_gemm_u<<<NS, 640, 0, stream>>>(x, Uall, bUall, u);
    k_stock<<<NS, 256, 0, stream>>>(u, ti, Wall, bWall, Wd, bWd, W1, b1, W2, b2,
                                    V, bV, Wih, bih, bhh, lin_w, lin_b, out);
}

// Round 2
// 2828.366 us; speedup vs baseline: 1.0023x; 1.0023x over previous
//
#include <hip/hip_runtime.h>
#include <cstddef>

#define NS 512
#define NL 5
#define NT 20
#define NE 768
#define NH 64
#define NG 256   // 4*H
#define BK 16

__device__ __forceinline__ float sigf(float x) { return 1.0f / (1.0f + expf(-x)); }

// ---------------------------------------------------------------------------
// Kernel 1: u[s][t][l][g] = sum_e x[s][l][t][e] * Uall[s][e][g] + bUall[s][g]
// one block per stock, 640 threads; thread tile = 10 rows x 4 cols.
// __launch_bounds__(640, 1): without the ",1" the compiler targeted 6
// waves/EU -> 84-VGPR cap -> acc[10][4] spilled to scratch (~5 GB traffic,
// measured round 1: WRITE_SIZE 5.24 GB vs 52 MB of real output).
// ---------------------------------------------------------------------------
__global__ __launch_bounds__(640, 1) void k_gemm_u(
    const float* __restrict__ x, const float* __restrict__ U,
    const float* __restrict__ bU, float* __restrict__ u)
{
    __shared__ float xs[100 * BK];   // x tile [row][k]
    __shared__ float Us[BK * NG];    // U tile [k][c]
    const int s = blockIdx.x;
    const int tid = threadIdx.x;
    const float* xg = x + (size_t)s * (NL * NT * NE);
    const float* Ug = U + (size_t)s * (NE * NG);
    const int rg = tid >> 6;    // wave id 0..9 -> row group (wave-uniform)
    const int cg = tid & 63;
    const int r0 = rg * 10;
    const int c0 = cg * 4;
    float acc[10][4];
    #pragma unroll
    for (int i = 0; i < 10; ++i)
        acc[i][0] = acc[i][1] = acc[i][2] = acc[i][3] = 0.0f;

    for (int e0 = 0; e0 < NE; e0 += BK) {
        if (tid < 400) {
            int row = tid >> 2;
            int kq = (tid & 3) * 4;
            *(float4*)&xs[row * BK + kq] =
                *(const float4*)(xg + (size_t)row * NE + e0 + kq);
        }
        {
            int i = tid;
            if (i < 1024) {
                int k = i >> 6, c4 = (i & 63) * 4;
                *(float4*)&Us[k * NG + c4] =
                    *(const float4*)(Ug + (size_t)(e0 + k) * NG + c4);
            }
            i = tid + 640;
            if (i < 1024) {
                int k = i >> 6, c4 = (i & 63) * 4;
                *(float4*)&Us[k * NG + c4] =
                    *(const float4*)(Ug + (size_t)(e0 + k) * NG + c4);
            }
        }
        __syncthreads();
        #pragma unroll
        for (int k4 = 0; k4 < BK; k4 += 4) {
            float4 uq0 = *(const float4*)&Us[(k4 + 0) * NG + c0];
            float4 uq1 = *(const float4*)&Us[(k4 + 1) * NG + c0];
            float4 uq2 = *(const float4*)&Us[(k4 + 2) * NG + c0];
            float4 uq3 = *(const float4*)&Us[(k4 + 3) * NG + c0];
            #pragma unroll
            for (int rr = 0; rr < 10; ++rr) {
                float4 xv = *(const float4*)&xs[(r0 + rr) * BK + k4];
                acc[rr][0] += xv.x * uq0.x + xv.y * uq1.x + xv.z * uq2.x + xv.w * uq3.x;
                acc[rr][1] += xv.x * uq0.y + xv.y * uq1.y + xv.z * uq2.y + xv.w * uq3.y;
                acc[rr][2] += xv.x * uq0.z + xv.y * uq1.z + xv.z * uq2.z + xv.w * uq3.z;
                acc[rr][3] += xv.x * uq0.w + xv.y * uq1.w + xv.z * uq2.w + xv.w * uq3.w;
            }
        }
        __syncthreads();
    }
    float4 bv = *(const float4*)(bU + (size_t)s * NG + c0);
    #pragma unroll
    for (int rr = 0; rr < 10; ++rr) {
        int r = r0 + rr;
        int l = r / 20, t = r % 20;   // x row index r = l*T + t
        float4 o;
        o.x = acc[rr][0] + bv.x;
        o.y = acc[rr][1] + bv.y;
        o.z = acc[rr][2] + bv.z;
        o.w = acc[rr][3] + bv.w;
        *(float4*)(u + (((size_t)s * NT + t) * NL + l) * NG + c0) = o;
    }
}

// ---------------------------------------------------------------------------
// Kernel 2: per-stock TimeLSTM + text attention + day LSTM + day attention + head
// one block per stock, 256 threads. Phase-aliased LDS layout (64.3 KB).
// __launch_bounds__(256, 2): VGPR cap 256 so wreg[64] stays in registers
// (grid is 2 blocks/CU anyway -> 8 waves/CU matches 2 waves/EU).
// ---------------------------------------------------------------------------
#define OF_FULL  0
#define OF_REGA  6400
#define OF_REGB  10496
#define OF_CS    14592
#define OF_HS    14912
#define OF_CA    15232
#define OF_TQ    15552
#define OF_CB0   15872
#define OF_CB1   15936
#define OF_CB2   16000
#define OF_BV    16064
#define SM_TOT   16065

__global__ __launch_bounds__(256, 2) void k_stock(
    const float* __restrict__ u, const float* __restrict__ ti,
    const float* __restrict__ Wall, const float* __restrict__ bWall,
    const float* __restrict__ Wd, const float* __restrict__ bWd,
    const float* __restrict__ W1, const float* __restrict__ b1,
    const float* __restrict__ W2, const float* __restrict__ b2,
    const float* __restrict__ V, const float* __restrict__ bV,
    const float* __restrict__ Wih, const float* __restrict__ bih,
    const float* __restrict__ bhh, const float* __restrict__ lin_w,
    const float* __restrict__ lin_b, float* __restrict__ out)
{
    __shared__ float sm[SM_TOT];
    const int s = blockIdx.x;
    const int tid = threadIdx.x;
    const float* ug = u + (size_t)s * NT * NL * NG;

    // ---- init: Wall column in registers, Wd/bWd/ts to LDS, zero state ----
    float wreg[NH];
    #pragma unroll
    for (int k = 0; k < NH; ++k)
        wreg[k] = Wall[((size_t)s * NH + k) * NG + tid];
    const float bwall_r = bWall[(size_t)s * NG + tid];

    for (int i = tid; i < NH * NH; i += 256)
        sm[OF_REGA + i] = Wd[(size_t)s * NH * NH + i];
    if (tid < NH) sm[OF_CB0 + tid] = bWd[(size_t)s * NH + tid];
    if (tid < NL * NT) sm[OF_TQ + tid] = ti[(size_t)s * NL * NT + tid];
    for (int idx = tid; idx < NL * NH; idx += 256) {
        sm[OF_CS + idx] = 0.0f;
        sm[OF_HS + idx] = 0.0f;
    }
    float uc[NL];
    #pragma unroll
    for (int l = 0; l < NL; ++l)
        uc[l] = ug[(size_t)l * NG + tid];
    __syncthreads();

    // ---- TimeLSTM over T steps (gate order f,i,o,c_tmp; ALL sigmoid) ----
    for (int t = 0; t < NT; ++t) {
        float un[NL];
        if (t + 1 < NT) {
            #pragma unroll
            for (int l = 0; l < NL; ++l)
                un[l] = ug[(size_t)((t + 1) * NL + l) * NG + tid];
        } else {
            #pragma unroll
            for (int l = 0; l < NL; ++l) un[l] = 0.0f;
        }
        // gate pre-activation for column tid (u already includes bUall)
        float gv[NL];
        #pragma unroll
        for (int l = 0; l < NL; ++l) gv[l] = bwall_r + uc[l];
        #pragma unroll
        for (int k4 = 0; k4 < NH; k4 += 4) {
            #pragma unroll
            for (int l = 0; l < NL; ++l) {
                float4 hv = *(const float4*)&sm[OF_HS + l * NH + k4];
                gv[l] += hv.x * wreg[k4] + hv.y * wreg[k4 + 1] +
                         hv.z * wreg[k4 + 2] + hv.w * wreg[k4 + 3];
            }
        }
        #pragma unroll
        for (int l = 0; l < NL; ++l)
            sm[OF_REGB + l * NG + tid] = sigf(gv[l]);
        // c_s1 = tanh(c@Wd + bWd); c_adj = c - c_s1 + c_s1*ts
        for (int idx = tid; idx < NL * NH; idx += 256) {
            int l = idx >> 6, hh = idx & 63;
            float ssum = sm[OF_CB0 + hh];
            #pragma unroll
            for (int k4 = 0; k4 < NH; k4 += 4) {
                float4 cv = *(const float4*)&sm[OF_CS + l * NH + k4];
                ssum += cv.x * sm[OF_REGA + (k4 + 0) * NH + hh]
                      + cv.y * sm[OF_REGA + (k4 + 1) * NH + hh]
                      + cv.z * sm[OF_REGA + (k4 + 2) * NH + hh]
                      + cv.w * sm[OF_REGA + (k4 + 3) * NH + hh];
            }
            float cs1 = tanhf(ssum);
            float tsv = sm[OF_TQ + l * NT + t];
            sm[OF_CA + idx] = sm[OF_CS + idx] - cs1 + cs1 * tsv;
        }
        __syncthreads();
        for (int idx = tid; idx < NL * NH; idx += 256) {
            int l = idx >> 6, hh = idx & 63;
            float f  = sm[OF_REGB + l * NG + hh];
            float ii = sm[OF_REGB + l * NG + 64 + hh];
            float oo = sm[OF_REGB + l * NG + 128 + hh];
            float ct = sm[OF_REGB + l * NG + 192 + hh];
            float cn = f * sm[OF_CA + idx] + ii * ct;
            sm[OF_CS + idx] = cn;
            sm[OF_HS + idx] = oo * tanhf(cn);
            sm[OF_FULL + (l * NT + t) * NH + hh] = oo;
        }
        __syncthreads();
        #pragma unroll
        for (int l = 0; l < NL; ++l) uc[l] = un[l];
    }

    // ---- load attention weights (Wd/gbufR/bWd now dead) ----
    for (int i = tid; i < NH * NH; i += 256) {
        sm[OF_REGA + i] = W1[(size_t)s * NH * NH + i];
        sm[OF_REGB + i] = W2[(size_t)s * NH * NH + i];
    }
    if (tid < NH) {
        sm[OF_CB0 + tid] = b1[(size_t)s * NH + tid];
        sm[OF_CB1 + tid] = b2[(size_t)s * NH + tid];
        sm[OF_CB2 + tid] = V[(size_t)s * NH + tid];
    }
    if (tid == 0) sm[OF_BV] = bV[s];
    __syncthreads();

    // q = h_fin @ W1 + b1
    for (int idx = tid; idx < NL * NH; idx += 256) {
        int l = idx >> 6, hh = idx & 63;
        float qv = sm[OF_CB0 + hh];
        #pragma unroll
        for (int k4 = 0; k4 < NH; k4 += 4) {
            float4 hv = *(const float4*)&sm[OF_HS + l * NH + k4];
            qv += hv.x * sm[OF_REGA + (k4 + 0) * NH + hh]
                + hv.y * sm[OF_REGA + (k4 + 1) * NH + hh]
                + hv.z * sm[OF_REGA + (k4 + 2) * NH + hh]
                + hv.w * sm[OF_REGA + (k4 + 3) * NH + hh];
        }
        sm[OF_TQ + idx] = qv;
    }
    __syncthreads();

    // scores: one wave per (l,t); score = tanh(q + full@W2 + b2) . V + bV
    const int wid = tid >> 6, lane = tid & 63;
    for (int lt = wid; lt < NL * NT; lt += 4) {
        int l = lt / NT;
        float v = sm[OF_TQ + l * NH + lane] + sm[OF_CB1 + lane];
        #pragma unroll
        for (int k4 = 0; k4 < NH; k4 += 4) {
            float4 fv = *(const float4*)&sm[OF_FULL + lt * NH + k4];
            v += fv.x * sm[OF_REGB + (k4 + 0) * NH + lane]
               + fv.y * sm[OF_REGB + (k4 + 1) * NH + lane]
               + fv.z * sm[OF_REGB + (k4 + 2) * NH + lane]
               + fv.w * sm[OF_REGB + (k4 + 3) * NH + lane];
        }
        v = tanhf(v) * sm[OF_CB2 + lane];
        #pragma unroll
        for (int m = 32; m > 0; m >>= 1) v += __shfl_xor(v, m, 64);
        if (lane == 0) sm[OF_CS + lt] = v + sm[OF_BV];
    }
    __syncthreads();

    // softmax over t per l (stable)
    if (tid < NL) {
        float mx = -1e30f;
        for (int t = 0; t < NT; ++t) mx = fmaxf(mx, sm[OF_CS + tid * NT + t]);
        float sum = 0.0f;
        for (int t = 0; t < NT; ++t) {
            float e = expf(sm[OF_CS + tid * NT + t] - mx);
            sm[OF_CS + tid * NT + t] = e;
            sum += e;
        }
        float inv = 1.0f / sum;
        for (int t = 0; t < NT; ++t) sm[OF_CS + tid * NT + t] *= inv;
    }
    __syncthreads();

    // text_vec = sum_t aw * full
    for (int idx = tid; idx < NL * NH; idx += 256) {
        int l = idx >> 6, hh = idx & 63;
        float sv = 0.0f;
        #pragma unroll
        for (int t = 0; t < NT; ++t)
            sv += sm[OF_CS + l * NT + t] * sm[OF_FULL + (l * NT + t) * NH + hh];
        sm[OF_CA + idx] = sv;   // tv
    }
    __syncthreads();

    // day LSTM: g = tv@Wih + bih + bhh (h0=0); gate order i,f,g,o
    {
        float bsum = bih[(size_t)s * NG + tid] + bhh[(size_t)s * NG + tid];
        float dsum[NL];
        #pragma unroll
        for (int l = 0; l < NL; ++l) dsum[l] = bsum;
        for (int k = 0; k < NH; ++k) {
            float wk = Wih[((size_t)s * NH + k) * NG + tid];
            #pragma unroll
            for (int l = 0; l < NL; ++l)
                dsum[l] += sm[OF_CA + l * NH + k] * wk;
        }
        #pragma unroll
        for (int l = 0; l < NL; ++l)
            sm[OF_FULL + l * NG + tid] = dsum[l];   // gbufL (full is dead)
    }
    __syncthreads();
    for (int idx = tid; idx < NL * NH; idx += 256) {
        int l = idx >> 6, hh = idx & 63;
        float gi = sm[OF_FULL + l * NG + hh];
        float gg = sm[OF_FULL + l * NG + 128 + hh];
        float go = sm[OF_FULL + l * NG + 192 + hh];
        float cd = sigf(gi) * tanhf(gg);
        sm[OF_FULL + 1536 + idx] = sigf(go) * tanhf(cd);   // hd
    }
    __syncthreads();

    // day attention: s2 = tanh(hd@W1 + b1 + hd@W2 + b2) . V + bV, softmax over L
    for (int l = wid; l < NL; l += 4) {
        float v = sm[OF_CB0 + lane] + sm[OF_CB1 + lane];
        #pragma unroll
        for (int k4 = 0; k4 < NH; k4 += 4) {
            float4 hv = *(const float4*)&sm[OF_FULL + 1536 + l * NH + k4];
            v += hv.x * (sm[OF_REGA + (k4 + 0) * NH + lane] + sm[OF_REGB + (k4 + 0) * NH + lane])
               + hv.y * (sm[OF_REGA + (k4 + 1) * NH + lane] + sm[OF_REGB + (k4 + 1) * NH + lane])
               + hv.z * (sm[OF_REGA + (k4 + 2) * NH + lane] + sm[OF_REGB + (k4 + 2) * NH + lane])
               + hv.w * (sm[OF_REGA + (k4 + 3) * NH + lane] + sm[OF_REGB + (k4 + 3) * NH + lane]);
        }
        v = tanhf(v) * sm[OF_CB2 + lane];
        #pragma unroll
        for (int m = 32; m > 0; m >>= 1) v += __shfl_xor(v, m, 64);
        if (lane == 0) sm[OF_CS + l] = v + sm[OF_BV];
    }
    __syncthreads();
    if (tid == 0) {
        float mx = -1e30f;
        for (int l = 0; l < NL; ++l) mx = fmaxf(mx, sm[OF_CS + l]);
        float sum = 0.0f;
        for (int l = 0; l < NL; ++l) {
            float e = expf(sm[OF_CS + l] - mx);
            sm[OF_CS + l] = e;
            sum += e;
        }
        float inv = 1.0f / sum;
        for (int l = 0; l < NL; ++l) sm[OF_CS + l] *= inv;
    }
    __syncthreads();

    // ft = sum_l aw2*hd ; out = leaky_relu(ft . lin_w + lin_b)
    if (tid < NH) {
        float fv = 0.0f;
        #pragma unroll
        for (int l = 0; l < NL; ++l)
            fv += sm[OF_CS + l] * sm[OF_FULL + 1536 + l * NH + tid];
        fv *= lin_w[tid];
        #pragma unroll
        for (int m = 32; m > 0; m >>= 1) fv += __shfl_xor(fv, m, 64);
        if (tid == 0) {
            float val = fv + lin_b[0];
            out[s] = val > 0.0f ? val : 0.01f * val;
        }
    }
}

extern "C" void kernel_launch(void* const* d_in, const int* in_sizes, int n_in,
                              void* d_out, int out_size, void* d_ws, size_t ws_size,
                              hipStream_t stream) {
    (void)in_sizes; (void)n_in; (void)out_size; (void)ws_size;
    const float* x     = (const float*)d_in[0];
    const float* ti    = (const float*)d_in[1];
    const float* Wall  = (const float*)d_in[2];
    const float* bWall = (const float*)d_in[3];
    const float* Uall  = (const float*)d_in[4];
    const float* bUall = (const float*)d_in[5];
    const float* Wd    = (const float*)d_in[6];
    const float* bWd   = (const float*)d_in[7];
    const float* W1    = (const float*)d_in[8];
    const float* b1    = (const float*)d_in[9];
    const float* W2    = (const float*)d_in[10];
    const float* b2    = (const float*)d_in[11];
    const float* V     = (const float*)d_in[12];
    const float* bV    = (const float*)d_in[13];
    const float* Wih   = (const float*)d_in[14];
    const float* bih   = (const float*)d_in[16];
    const float* bhh   = (const float*)d_in[17];
    const float* lin_w = (const float*)d_in[18];
    const float* lin_b = (const float*)d_in[19];
    float* out = (float*)d_out;
    float* u = (float*)d_ws;   // [S][T][L][NG] = 52.4 MB

    k_gemm_u<<<NS, 640, 0, stream>>>(x, Uall, bUall, u);
    k_stock<<<NS, 256, 0, stream>>>(u, ti, Wall, bWall, Wd, bWd, W1, b1, W2, b2,
                                    V, bV, Wih, bih, bhh, lin_w, lin_b, out);
}

// Round 3
// 1384.987 us; speedup vs baseline: 2.0470x; 2.0422x over previous
//
#include <hip/hip_runtime.h>
#include <cstddef>

#define NS 512
#define NL 5
#define NT 20
#define NE 768
#define NH 64
#define NG 256   // 4*H
#define BK 16

__device__ __forceinline__ float sigf(float x) { return 1.0f / (1.0f + expf(-x)); }

// ---------------------------------------------------------------------------
// Kernel 1: u[s][t][l][g] = sum_e x[s][l][t][e] * Uall[s][e][g] + bUall[s][g]
// v2: 2 blocks per stock (128-col halves), 640 threads, thread tile 10x2.
// Peak register pressure ~50 (acc 20 + uq 8 + xv 4 + addr) -- fits under the
// 84-VGPR heuristic cap that spilled the r1 10x4 tile (measured: 5.24 GB
// scratch WRITE_SIZE). Us read as two conflict-free b32 columns.
// ---------------------------------------------------------------------------
__global__ __launch_bounds__(640) void k_gemm_u(
    const float* __restrict__ x, const float* __restrict__ U,
    const float* __restrict__ bU, float* __restrict__ u)
{
    __shared__ float xs[100 * BK];    // 6400 B
    __shared__ float Us[BK * 128];    // 8192 B
    const int bid = blockIdx.x;
    const int s = bid >> 1, half = bid & 1;
    const int tid = threadIdx.x;
    const float* xg = x + (size_t)s * (NL * NT * NE);
    const float* Ug = U + (size_t)s * (NE * NG) + half * 128;
    const int wave = tid >> 6, lane = tid & 63;
    const int r0 = wave * 10;
    float acc0[10], acc1[10];   // cols (lane, lane+64) within the 128-half
    #pragma unroll
    for (int i = 0; i < 10; ++i) { acc0[i] = 0.0f; acc1[i] = 0.0f; }

    for (int e0 = 0; e0 < NE; e0 += BK) {
        if (tid < 400) {
            int row = tid >> 2;
            int kq = (tid & 3) * 4;
            *(float4*)&xs[row * BK + kq] =
                *(const float4*)(xg + (size_t)row * NE + e0 + kq);
        }
        if (tid < 512) {
            int k = tid >> 5, c4 = (tid & 31) * 4;
            *(float4*)&Us[k * 128 + c4] =
                *(const float4*)(Ug + (size_t)(e0 + k) * NG + c4);
        }
        __syncthreads();
        #pragma unroll
        for (int k4 = 0; k4 < BK; k4 += 4) {
            float ua0 = Us[(k4 + 0) * 128 + lane];
            float ua1 = Us[(k4 + 1) * 128 + lane];
            float ua2 = Us[(k4 + 2) * 128 + lane];
            float ua3 = Us[(k4 + 3) * 128 + lane];
            float ub0 = Us[(k4 + 0) * 128 + 64 + lane];
            float ub1 = Us[(k4 + 1) * 128 + 64 + lane];
            float ub2 = Us[(k4 + 2) * 128 + 64 + lane];
            float ub3 = Us[(k4 + 3) * 128 + 64 + lane];
            #pragma unroll
            for (int rr = 0; rr < 10; ++rr) {
                float4 xv = *(const float4*)&xs[(r0 + rr) * BK + k4];
                acc0[rr] += xv.x * ua0 + xv.y * ua1 + xv.z * ua2 + xv.w * ua3;
                acc1[rr] += xv.x * ub0 + xv.y * ub1 + xv.z * ub2 + xv.w * ub3;
            }
        }
        __syncthreads();
    }
    const float bv0 = bU[(size_t)s * NG + half * 128 + lane];
    const float bv1 = bU[(size_t)s * NG + half * 128 + 64 + lane];
    #pragma unroll
    for (int rr = 0; rr < 10; ++rr) {
        int r = r0 + rr;
        int l = r / 20, t = r % 20;
        size_t base = (((size_t)s * NT + t) * NL + l) * NG + half * 128 + lane;
        u[base]      = acc0[rr] + bv0;
        u[base + 64] = acc1[rr] + bv1;
    }
}

// ---------------------------------------------------------------------------
// Kernel 2 v2: per-stock TimeLSTM + attention + day LSTM + head.
// 320 threads (5 waves == 5*64 (l,h) items). Wall/Wd live in LDS and are
// read as conflict-free per-column b32 (bank = tid%32) -- no 64-reg
// per-thread weight array, so no scratch spill at the 84-VGPR cap.
// LDS 119 KB -> 1 block/CU, 512 blocks = 2 rounds.
// ---------------------------------------------------------------------------
#define WALL  0        // 16384 fl; aliased after recurrence: W1@0, W2@4096
#define W1OFF 0
#define W2OFF 4096
#define WD    16384    // 4096 fl
#define FULLO 20480    // 6400 fl: o-gates [l][t][h]
#define HS    26880    // 320
#define CS    27200    // 320
#define CA    27520    // 320
#define TQ    27840    // 320: q, then hd
#define GATES 28160    // 1280
#define TS    29440    // 100
#define B0    29540    // 64: bWd -> b1
#define B1    29604    // 64: b2
#define BVV   29668    // 64: V
#define SC    29732    // 100: scores
#define BV1   29832    // 1: bV
#define SMTOT 29833

__global__ __launch_bounds__(320) void k_stock(
    const float* __restrict__ u, const float* __restrict__ ti,
    const float* __restrict__ Wall, const float* __restrict__ bWall,
    const float* __restrict__ Wd, const float* __restrict__ bWd,
    const float* __restrict__ W1, const float* __restrict__ b1,
    const float* __restrict__ W2, const float* __restrict__ b2,
    const float* __restrict__ V, const float* __restrict__ bV,
    const float* __restrict__ Wih, const float* __restrict__ bih,
    const float* __restrict__ bhh, const float* __restrict__ lin_w,
    const float* __restrict__ lin_b, float* __restrict__ out)
{
    __shared__ float sm[SMTOT];
    const int s = blockIdx.x;
    const int tid = threadIdx.x;
    const int lq = tid >> 6, hh = tid & 63;   // (l, h) item for 320-wide ops
    const int lane = hh;
    const float* ug = u + (size_t)s * NT * NL * NG;

    // ---- init ----
    for (int i = tid; i < 4096; i += 320)
        *(float4*)&sm[WALL + i * 4] = *(const float4*)(Wall + (size_t)s * 16384 + i * 4);
    for (int i = tid; i < 1024; i += 320)
        *(float4*)&sm[WD + i * 4] = *(const float4*)(Wd + (size_t)s * 4096 + i * 4);
    if (tid < NH) sm[B0 + tid] = bWd[(size_t)s * NH + tid];
    if (tid < NL * NT) sm[TS + tid] = ti[(size_t)s * NL * NT + tid];
    sm[HS + tid] = 0.0f;
    sm[CS + tid] = 0.0f;
    float bwall_r = 0.0f, uc[NL];
    if (tid < NG) {
        bwall_r = bWall[(size_t)s * NG + tid];
        #pragma unroll
        for (int l = 0; l < NL; ++l)
            uc[l] = ug[(size_t)l * NG + tid];
    }
    __syncthreads();

    // ---- TimeLSTM over T steps (gate order f,i,o,c_tmp; ALL sigmoid) ----
    for (int t = 0; t < NT; ++t) {
        float un[NL];
        if (tid < NG) {
            if (t + 1 < NT) {
                #pragma unroll
                for (int l = 0; l < NL; ++l)
                    un[l] = ug[(size_t)((t + 1) * NL + l) * NG + tid];
            } else {
                #pragma unroll
                for (int l = 0; l < NL; ++l) un[l] = 0.0f;
            }
            // gates: gv[l] = bWall + u_t + sum_k h[l][k] * Wall[k][tid]
            float gv[NL];
            #pragma unroll
            for (int l = 0; l < NL; ++l) gv[l] = bwall_r + uc[l];
            for (int k4 = 0; k4 < NH; k4 += 4) {
                float w0 = sm[WALL + (k4 + 0) * NG + tid];
                float w1 = sm[WALL + (k4 + 1) * NG + tid];
                float w2 = sm[WALL + (k4 + 2) * NG + tid];
                float w3 = sm[WALL + (k4 + 3) * NG + tid];
                #pragma unroll
                for (int l = 0; l < NL; ++l) {
                    float4 hv = *(const float4*)&sm[HS + l * NH + k4];
                    gv[l] += hv.x * w0 + hv.y * w1 + hv.z * w2 + hv.w * w3;
                }
            }
            #pragma unroll
            for (int l = 0; l < NL; ++l)
                sm[GATES + l * NG + tid] = sigf(gv[l]);
        }
        // c_s1 = tanh(c@Wd + bWd); c_adj = c - c_s1 + c_s1*ts  (all 320)
        {
            float ssum = sm[B0 + hh];
            for (int k4 = 0; k4 < NH; k4 += 4) {
                float4 cv = *(const float4*)&sm[CS + lq * NH + k4];
                ssum += cv.x * sm[WD + (k4 + 0) * NH + hh]
                      + cv.y * sm[WD + (k4 + 1) * NH + hh]
                      + cv.z * sm[WD + (k4 + 2) * NH + hh]
                      + cv.w * sm[WD + (k4 + 3) * NH + hh];
            }
            float cs1 = tanhf(ssum);
            sm[CA + tid] = sm[CS + tid] - cs1 + cs1 * sm[TS + lq * NT + t];
        }
        __syncthreads();
        {
            float f  = sm[GATES + lq * NG + hh];
            float ii = sm[GATES + lq * NG + 64 + hh];
            float oo = sm[GATES + lq * NG + 128 + hh];
            float ct = sm[GATES + lq * NG + 192 + hh];
            float cn = f * sm[CA + tid] + ii * ct;
            sm[CS + tid] = cn;
            sm[HS + tid] = oo * tanhf(cn);
            sm[FULLO + (lq * NT + t) * NH + hh] = oo;
        }
        __syncthreads();
        if (tid < NG) {
            #pragma unroll
            for (int l = 0; l < NL; ++l) uc[l] = un[l];
        }
    }

    // ---- attention weights overwrite Wall's LDS (dead now) ----
    for (int i = tid; i < 1024; i += 320)
        *(float4*)&sm[W1OFF + i * 4] = *(const float4*)(W1 + (size_t)s * 4096 + i * 4);
    for (int i = tid; i < 1024; i += 320)
        *(float4*)&sm[W2OFF + i * 4] = *(const float4*)(W2 + (size_t)s * 4096 + i * 4);
    if (tid < NH) {
        sm[B0 + tid]  = b1[(size_t)s * NH + tid];
        sm[B1 + tid]  = b2[(size_t)s * NH + tid];
        sm[BVV + tid] = V[(size_t)s * NH + tid];
    }
    if (tid == 0) sm[BV1] = bV[s];
    __syncthreads();

    // q = h_fin @ W1 + b1   (320 items)
    {
        float qv = sm[B0 + hh];
        for (int k4 = 0; k4 < NH; k4 += 4) {
            float4 hv = *(const float4*)&sm[HS + lq * NH + k4];
            qv += hv.x * sm[W1OFF + (k4 + 0) * NH + hh]
                + hv.y * sm[W1OFF + (k4 + 1) * NH + hh]
                + hv.z * sm[W1OFF + (k4 + 2) * NH + hh]
                + hv.w * sm[W1OFF + (k4 + 3) * NH + hh];
        }
        sm[TQ + tid] = qv;
    }
    __syncthreads();

    // scores: one wave per (l,t) item; 100 items over 5 waves
    for (int lt = lq; lt < NL * NT; lt += 5) {
        int l = lt / NT;
        float v = sm[TQ + l * NH + lane] + sm[B1 + lane];
        for (int k4 = 0; k4 < NH; k4 += 4) {
            float4 fv = *(const float4*)&sm[FULLO + lt * NH + k4];
            v += fv.x * sm[W2OFF + (k4 + 0) * NH + lane]
               + fv.y * sm[W2OFF + (k4 + 1) * NH + lane]
               + fv.z * sm[W2OFF + (k4 + 2) * NH + lane]
               + fv.w * sm[W2OFF + (k4 + 3) * NH + lane];
        }
        v = tanhf(v) * sm[BVV + lane];
        #pragma unroll
        for (int m = 32; m > 0; m >>= 1) v += __shfl_xor(v, m, 64);
        if (lane == 0) sm[SC + lt] = v + sm[BV1];
    }
    __syncthreads();

    // softmax over t per l
    if (tid < NL) {
        float mx = -1e30f;
        for (int t = 0; t < NT; ++t) mx = fmaxf(mx, sm[SC + tid * NT + t]);
        float sum = 0.0f;
        for (int t = 0; t < NT; ++t) {
            float e = expf(sm[SC + tid * NT + t] - mx);
            sm[SC + tid * NT + t] = e;
            sum += e;
        }
        float inv = 1.0f / sum;
        for (int t = 0; t < NT; ++t) sm[SC + tid * NT + t] *= inv;
    }
    __syncthreads();

    // text_vec -> CA
    {
        float sv = 0.0f;
        #pragma unroll
        for (int t = 0; t < NT; ++t)
            sv += sm[SC + lq * NT + t] * sm[FULLO + (lq * NT + t) * NH + hh];
        sm[CA + tid] = sv;
    }
    __syncthreads();

    // day LSTM: g = tv@Wih + bih + bhh; order i,f,g,o
    if (tid < NG) {
        float bsum = bih[(size_t)s * NG + tid] + bhh[(size_t)s * NG + tid];
        float d[NL];
        #pragma unroll
        for (int l = 0; l < NL; ++l) d[l] = bsum;
        for (int k = 0; k < NH; ++k) {
            float wk = Wih[((size_t)s * NH + k) * NG + tid];
            #pragma unroll
            for (int l = 0; l < NL; ++l)
                d[l] += sm[CA + l * NH + k] * wk;
        }
        #pragma unroll
        for (int l = 0; l < NL; ++l)
            sm[GATES + l * NG + tid] = d[l];
    }
    __syncthreads();
    {
        float gi = sm[GATES + lq * NG + hh];
        float gg = sm[GATES + lq * NG + 128 + hh];
        float go = sm[GATES + lq * NG + 192 + hh];
        float cd = sigf(gi) * tanhf(gg);
        sm[TQ + tid] = sigf(go) * tanhf(cd);    // hd (q is dead)
    }
    __syncthreads();

    // day attention: wave lq handles l=lq (<5)
    {
        float v = sm[B0 + lane] + sm[B1 + lane];
        for (int k4 = 0; k4 < NH; k4 += 4) {
            float4 hv = *(const float4*)&sm[TQ + lq * NH + k4];
            v += hv.x * (sm[W1OFF + (k4 + 0) * NH + lane] + sm[W2OFF + (k4 + 0) * NH + lane])
               + hv.y * (sm[W1OFF + (k4 + 1) * NH + lane] + sm[W2OFF + (k4 + 1) * NH + lane])
               + hv.z * (sm[W1OFF + (k4 + 2) * NH + lane] + sm[W2OFF + (k4 + 2) * NH + lane])
               + hv.w * (sm[W1OFF + (k4 + 3) * NH + lane] + sm[W2OFF + (k4 + 3) * NH + lane]);
        }
        v = tanhf(v) * sm[BVV + lane];
        #pragma unroll
        for (int m = 32; m > 0; m >>= 1) v += __shfl_xor(v, m, 64);
        if (lane == 0) sm[SC + lq] = v + sm[BV1];
    }
    __syncthreads();
    if (tid == 0) {
        float mx = -1e30f;
        for (int l = 0; l < NL; ++l) mx = fmaxf(mx, sm[SC + l]);
        float sum = 0.0f;
        for (int l = 0; l < NL; ++l) {
            float e = expf(sm[SC + l] - mx);
            sm[SC + l] = e;
            sum += e;
        }
        float inv = 1.0f / sum;
        for (int l = 0; l < NL; ++l) sm[SC + l] *= inv;
    }
    __syncthreads();

    if (tid < NH) {
        float fv = 0.0f;
        #pragma unroll
        for (int l = 0; l < NL; ++l)
            fv += sm[SC + l] * sm[TQ + l * NH + tid];
        fv *= lin_w[tid];
        #pragma unroll
        for (int m = 32; m > 0; m >>= 1) fv += __shfl_xor(fv, m, 64);
        if (tid == 0) {
            float val = fv + lin_b[0];
            out[s] = val > 0.0f ? val : 0.01f * val;
        }
    }
}

extern "C" void kernel_launch(void* const* d_in, const int* in_sizes, int n_in,
                              void* d_out, int out_size, void* d_ws, size_t ws_size,
                              hipStream_t stream) {
    (void)in_sizes; (void)n_in; (void)out_size; (void)ws_size;
    const float* x     = (const float*)d_in[0];
    const float* ti    = (const float*)d_in[1];
    const float* Wall  = (const float*)d_in[2];
    const float* bWall = (const float*)d_in[3];
    const float* Uall  = (const float*)d_in[4];
    const float* bUall = (const float*)d_in[5];
    const float* Wd    = (const float*)d_in[6];
    const float* bWd   = (const float*)d_in[7];
    const float* W1    = (const float*)d_in[8];
    const float* b1    = (const float*)d_in[9];
    const float* W2    = (const float*)d_in[10];
    const float* b2    = (const float*)d_in[11];
    const float* V     = (const float*)d_in[12];
    const float* bV    = (const float*)d_in[13];
    const float* Wih   = (const float*)d_in[14];
    const float* bih   = (const float*)d_in[16];
    const float* bhh   = (const float*)d_in[17];
    const float* lin_w = (const float*)d_in[18];
    const float* lin_b = (const float*)d_in[19];
    float* out = (float*)d_out;
    float* u = (float*)d_ws;   // [S][T][L][NG] = 52.4 MB

    k_gemm_u<<<NS * 2, 640, 0, stream>>>(x, Uall, bUall, u);
    k_stock<<<NS, 320, 0, stream>>>(u, ti, Wall, bWall, Wd, bWd, W1, b1, W2, b2,
                                    V, bV, Wih, bih, bhh, lin_w, lin_b, out);
}